// Round 7
// baseline (289.593 us; speedup 1.0000x reference)
//
#include <hip/hip_runtime.h>
#include <hip/hip_bf16.h>
#include <stdint.h>

#define DIM   1024
#define NH    16
#define HD    64
#define BATCH 2
#define SEQ   2048
#define MTOK  (BATCH*SEQ)   // 4096

typedef __attribute__((ext_vector_type(8))) short bf16x8;   // 8 bf16 (4 VGPRs)
typedef __attribute__((ext_vector_type(4))) float f32x4;    // MFMA C/D
typedef __attribute__((ext_vector_type(4))) unsigned short us4;

__device__ __forceinline__ unsigned short f2bf(float f) {
  union { __hip_bfloat16 h; unsigned short u; } c;
  c.h = __float2bfloat16(f);   // RNE
  return c.u;
}

// async global->LDS, 16B per lane; LDS dest = wave-uniform base + lane*16 (m97/m104).
__device__ __forceinline__ void gload_lds16(const unsigned short* g, unsigned short* l) {
  __builtin_amdgcn_global_load_lds(
      (const __attribute__((address_space(1))) unsigned int*)(uintptr_t)g,
      (__attribute__((address_space(3))) unsigned int*)(uintptr_t)l,
      16, 0, 0);
}

// ---------------------------------------------------------------- fused casts
// blockIdx.y: 0=x, 1=Wq, 2=Wk, 3=Wv, 4=Wo. One launch instead of five.
__global__ void cast_fused(const float* __restrict__ x,  const float* __restrict__ wq,
                           const float* __restrict__ wk, const float* __restrict__ wv,
                           const float* __restrict__ wo,
                           unsigned short* __restrict__ xb,
                           unsigned short* __restrict__ wqkvb,
                           unsigned short* __restrict__ wob) {
  const float* src; unsigned short* dst; int n;
  switch (blockIdx.y) {
    case 0:  src = x;  dst = xb;                n = MTOK * DIM; break;
    case 1:  src = wq; dst = wqkvb;             n = DIM * DIM;  break;
    case 2:  src = wk; dst = wqkvb +   DIM*DIM; n = DIM * DIM;  break;
    case 3:  src = wv; dst = wqkvb + 2*DIM*DIM; n = DIM * DIM;  break;
    default: src = wo; dst = wob;               n = DIM * DIM;  break;
  }
  int idx = (blockIdx.x * blockDim.x + threadIdx.x) * 4;
  const int stride = gridDim.x * blockDim.x * 4;
  for (; idx < n; idx += stride) {
    float4 v = *reinterpret_cast<const float4*>(src + idx);
    us4 o;
    o[0] = f2bf(v.x); o[1] = f2bf(v.y); o[2] = f2bf(v.z); o[3] = f2bf(v.w);
    *reinterpret_cast<us4*>(dst + idx) = o;
  }
}

// ---------------------------------------------------------------- GEMM (B^T): C[m][n] = sum_k A[m][k]*Bw[n][k]
// m97 structure: 128x128 tile, BK=32, 4 waves (2x2), 16x16x32 MFMA, global_load_lds w16.
// EPI=0: bf16 out routed to Qb[bh][t][d] (x0.125), Kb[bh][t][d], Vt[bh][d][t]
// EPI=1: f32 out row-major
template<int EPI>
__global__ __launch_bounds__(256)
void gemm_bt(const unsigned short* __restrict__ A,
             const unsigned short* __restrict__ Bw,
             int M, int N, int K, int ntn,
             unsigned short* __restrict__ Qb,
             unsigned short* __restrict__ Kb,
             unsigned short* __restrict__ Vt,
             float* __restrict__ Cf) {
  __shared__ __align__(16) unsigned short As[128 * 32];
  __shared__ __align__(16) unsigned short Bs[128 * 32];
  const int tid  = threadIdx.x;
  const int lane = tid & 63;
  const int w    = tid >> 6;          // wave 0..3
  const int wr   = w >> 1, wc = w & 1;

  // T1: XCD-aware bijective swizzle (both grids here are multiples of 8)
  const int nwg = gridDim.x;
  const int bid = blockIdx.x;
  const int swz = (nwg & 7) == 0 ? (bid & 7) * (nwg >> 3) + (bid >> 3) : bid;
  const int mt = swz / ntn, nt = swz % ntn;
  const int m0 = mt * 128, n0 = nt * 128;

  // staging: per wave 2 issues for A rows [w*32,w*32+32), same for B.
  // lane = srow*4 + c  ->  LDS offset lane*16B = srow*64B + c*16B  (row-linear match)
  const int srow = lane >> 2;         // 0..15
  const int scol = (lane & 3) << 3;   // 0,8,16,24
  const unsigned short* Ag = A  + (size_t)(m0 + w*32 + srow) * K + scol;
  const unsigned short* Bg = Bw + (size_t)(n0 + w*32 + srow) * K + scol;
  unsigned short* AsW0 = &As[(w*32     ) * 32];
  unsigned short* AsW1 = &As[(w*32 + 16) * 32];
  unsigned short* BsW0 = &Bs[(w*32     ) * 32];
  unsigned short* BsW1 = &Bs[(w*32 + 16) * 32];

  const int l15 = lane & 15;
  const int g8  = (lane >> 4) << 3;
  f32x4 acc[4][4] = {};

  for (int k0 = 0; k0 < K; k0 += 32) {
    gload_lds16(Ag + k0,                AsW0);
    gload_lds16(Ag + (size_t)16*K + k0, AsW1);
    gload_lds16(Bg + k0,                BsW0);
    gload_lds16(Bg + (size_t)16*K + k0, BsW1);
    __syncthreads();                     // compiler drains vmcnt(0) before s_barrier
    bf16x8 af[4], bfr[4];
#pragma unroll
    for (int i = 0; i < 4; ++i)
      af[i] = *(const bf16x8*)&As[(wr*64 + i*16 + l15) * 32 + g8];
#pragma unroll
    for (int j = 0; j < 4; ++j)
      bfr[j] = *(const bf16x8*)&Bs[(wc*64 + j*16 + l15) * 32 + g8];
#pragma unroll
    for (int i = 0; i < 4; ++i)
#pragma unroll
      for (int j = 0; j < 4; ++j)
        acc[i][j] = __builtin_amdgcn_mfma_f32_16x16x32_bf16(af[i], bfr[j], acc[i][j], 0, 0, 0);
    __syncthreads();
  }

  // C/D layout: col = lane&15, row = (lane>>4)*4 + reg  (m89-verified)
  const int r0 = m0 + wr*64 + ((lane >> 4) << 2);
  const int c0 = n0 + wc*64 + l15;
  if (EPI == 0) {
#pragma unroll
    for (int i = 0; i < 4; ++i) {
      const int row = r0 + i*16;
      const int bb  = row >> 11;       // /SEQ
      const int tt  = row & (SEQ - 1); // multiple of 4 -> us4 store 8B-aligned
#pragma unroll
      for (int j = 0; j < 4; ++j) {
        const int col   = c0 + j*16;
        const int which = col >> 10;
        const int hh    = (col & 1023) >> 6;
        const int dd    = col & 63;
        const int bhh   = bb * NH + hh;
        if (which == 0) {
#pragma unroll
          for (int r = 0; r < 4; ++r)
            Qb[((size_t)bhh * SEQ + tt + r) * HD + dd] = f2bf(acc[i][j][r] * 0.125f);
        } else if (which == 1) {
#pragma unroll
          for (int r = 0; r < 4; ++r)
            Kb[((size_t)bhh * SEQ + tt + r) * HD + dd] = f2bf(acc[i][j][r]);
        } else {
          us4 ov;
#pragma unroll
          for (int r = 0; r < 4; ++r) ov[r] = f2bf(acc[i][j][r]);
          *reinterpret_cast<us4*>(&Vt[((size_t)bhh * HD + dd) * SEQ + tt]) = ov;
        }
      }
    }
  } else {
#pragma unroll
    for (int i = 0; i < 4; ++i)
#pragma unroll
      for (int j = 0; j < 4; ++j)
#pragma unroll
        for (int r = 0; r < 4; ++r)
          Cf[(size_t)(r0 + i*16 + r) * N + c0 + j*16] = acc[i][j][r];
  }
}

// ---------------------------------------------------------------- flash attention
// 1 wave / block, 32 q-rows, KVBLK=64. K,V frags direct from global (L2/L3-resident,
// K+V = 16 MB total -> don't LDS-stage, Common-mistake #7). Q pre-scaled by 1/8.
// T5: setprio(1) around MFMA clusters — m191-verified +4-7% for independent
// 1-wave-block attention (waves at different phases give the scheduler a choice).
__global__ __launch_bounds__(64)
void attn_fwd(const unsigned short* __restrict__ Qb,
              const unsigned short* __restrict__ Kb,
              const unsigned short* __restrict__ Vt,
              unsigned short* __restrict__ AO) {
  __shared__ __align__(16) unsigned short P[32 * 72];  // +8 pad -> 2-way conflicts only (free, m136)
  const int lane = threadIdx.x;
  const int l15  = lane & 15;
  const int g    = lane >> 4;
  const int g8   = g << 3;
  const int qt   = gridDim.x - 1 - blockIdx.x;  // long q-tiles scheduled first
  const int q0   = qt * 32;
  const int bh   = blockIdx.y;
  const int b    = bh >> 4, h = bh & 15;

  const unsigned short* Qbh = Qb + (size_t)bh * SEQ * HD;
  const unsigned short* Kbh = Kb + (size_t)bh * SEQ * HD;
  const unsigned short* Vbh = Vt + (size_t)bh * HD * SEQ;

  // hoist Q fragments (A-frag: row = lane&15, k = (lane>>4)*8..+8 within each K=32 chunk)
  bf16x8 qf[2][2];
#pragma unroll
  for (int mm = 0; mm < 2; ++mm)
#pragma unroll
    for (int dd = 0; dd < 2; ++dd)
      qf[mm][dd] = *(const bf16x8*)&Qbh[(size_t)(q0 + mm*16 + l15) * HD + dd*32 + g8];

  f32x4 o[2][4] = {};
  float mrun[8], lrun[8];
#pragma unroll
  for (int i = 0; i < 8; ++i) { mrun[i] = -1e30f; lrun[i] = 0.f; }

  const int ntile = q0 / 64 + 1;
  for (int t = 0; t < ntile; ++t) {
    const int k0 = t * 64;
    f32x4 s[2][4] = {};
#pragma unroll
    for (int dd = 0; dd < 2; ++dd) {
      bf16x8 kf[4];
#pragma unroll
      for (int nn = 0; nn < 4; ++nn)
        kf[nn] = *(const bf16x8*)&Kbh[(size_t)(k0 + nn*16 + l15) * HD + dd*32 + g8];
      __builtin_amdgcn_s_setprio(1);
#pragma unroll
      for (int mm = 0; mm < 2; ++mm)
#pragma unroll
        for (int nn = 0; nn < 4; ++nn)
          s[mm][nn] = __builtin_amdgcn_mfma_f32_16x16x32_bf16(qf[mm][dd], kf[nn], s[mm][nn], 0, 0, 0);
      __builtin_amdgcn_s_setprio(0);
    }
    if (t == ntile - 1) {        // causal mask only on diagonal tile
#pragma unroll
      for (int mm = 0; mm < 2; ++mm)
#pragma unroll
        for (int nn = 0; nn < 4; ++nn) {
          const int kg = k0 + nn*16 + l15;
#pragma unroll
          for (int r = 0; r < 4; ++r) {
            const int qg = q0 + mm*16 + g*4 + r;
            if (kg > qg) s[mm][nn][r] = -1e30f;
          }
        }
    }
    // online softmax; S row = (lane>>4)*4+r (+mm*16), col = lane&15 (+nn*16).
    // shfl_xor {1,2,4,8} stays within the 16-lane group g -> reduces over this row's 16 cols.
#pragma unroll
    for (int mm = 0; mm < 2; ++mm)
#pragma unroll
      for (int r = 0; r < 4; ++r) {
        const int ri = mm*4 + r;
        float v = fmaxf(fmaxf(s[mm][0][r], s[mm][1][r]), fmaxf(s[mm][2][r], s[mm][3][r]));
        v = fmaxf(v, __shfl_xor(v, 1));
        v = fmaxf(v, __shfl_xor(v, 2));
        v = fmaxf(v, __shfl_xor(v, 4));
        v = fmaxf(v, __shfl_xor(v, 8));
        const float mnew  = fmaxf(mrun[ri], v);
        const float alpha = __expf(mrun[ri] - mnew);
        mrun[ri] = mnew;
        float rs = 0.f;
#pragma unroll
        for (int nn = 0; nn < 4; ++nn) {
          const float p = __expf(s[mm][nn][r] - mnew);
          s[mm][nn][r] = p;
          rs += p;
        }
        rs += __shfl_xor(rs, 1);
        rs += __shfl_xor(rs, 2);
        rs += __shfl_xor(rs, 4);
        rs += __shfl_xor(rs, 8);
        lrun[ri] = lrun[ri] * alpha + rs;
#pragma unroll
        for (int nn = 0; nn < 4; ++nn) o[mm][nn][r] *= alpha;
      }
    // P: C-layout -> LDS -> A-frag reshape
#pragma unroll
    for (int mm = 0; mm < 2; ++mm)
#pragma unroll
      for (int nn = 0; nn < 4; ++nn)
#pragma unroll
        for (int r = 0; r < 4; ++r)
          P[(mm*16 + g*4 + r) * 72 + nn*16 + l15] = f2bf(s[mm][nn][r]);
    __syncthreads();
    // PV: A=P[q][k], B=V[k][d] from Vt[d][t] (contiguous along t)
#pragma unroll
    for (int kk = 0; kk < 2; ++kk) {
      bf16x8 pa[2];
#pragma unroll
      for (int mm = 0; mm < 2; ++mm)
        pa[mm] = *(const bf16x8*)&P[(mm*16 + l15) * 72 + kk*32 + g8];
      __builtin_amdgcn_s_setprio(1);
#pragma unroll
      for (int nn = 0; nn < 4; ++nn) {
        bf16x8 vf = *(const bf16x8*)&Vbh[(size_t)(nn*16 + l15) * SEQ + k0 + kk*32 + g8];
#pragma unroll
        for (int mm = 0; mm < 2; ++mm)
          o[mm][nn] = __builtin_amdgcn_mfma_f32_16x16x32_bf16(pa[mm], vf, o[mm][nn], 0, 0, 0);
      }
      __builtin_amdgcn_s_setprio(0);
    }
    __syncthreads();
  }
  // normalize + store [b*SEQ+t][h*64+d] bf16
#pragma unroll
  for (int mm = 0; mm < 2; ++mm)
#pragma unroll
    for (int r = 0; r < 4; ++r) {
      const float inv = 1.0f / lrun[mm*4 + r];
      const int row = b*SEQ + q0 + mm*16 + g*4 + r;
#pragma unroll
      for (int nn = 0; nn < 4; ++nn)
        AO[(size_t)row * DIM + h*HD + nn*16 + l15] = f2bf(o[mm][nn][r] * inv);
    }
}

// ---------------------------------------------------------------- launch
extern "C" void kernel_launch(void* const* d_in, const int* in_sizes, int n_in,
                              void* d_out, int out_size, void* d_ws, size_t ws_size,
                              hipStream_t stream) {
  (void)in_sizes; (void)n_in; (void)out_size; (void)ws_size;
  const float* x  = (const float*)d_in[0];
  // d_in[1] = causal mask: deterministic (triu * f32-min), handled analytically in attn_fwd
  const float* Wq = (const float*)d_in[2];
  const float* Wk = (const float*)d_in[3];
  const float* Wv = (const float*)d_in[4];
  const float* Wo = (const float*)d_in[5];
  float* out = (float*)d_out;

  // workspace carve (ushorts), 40 MB total.
  // AO aliases x_bf: x_bf is dead after gemm_bt<0>, kernels serialize on stream.
  unsigned short* ws    = (unsigned short*)d_ws;
  unsigned short* x_bf  = ws;                                  // 4096x1024   [0, 4M)
  unsigned short* wqkv  = x_bf  + (size_t)MTOK * DIM;          // 3072x1024   [4M, 7M)
  unsigned short* wo_bf = wqkv  + (size_t)3 * DIM * DIM;       // 1024x1024   [7M, 8M)
  unsigned short* Qb    = wo_bf + (size_t)DIM * DIM;           // [32][2048][64] [8M,12M)
  unsigned short* Kb    = Qb    + (size_t)MTOK * DIM;          //             [12M,16M)
  unsigned short* Vt    = Kb    + (size_t)MTOK * DIM;          // [32][64][2048] [16M,20M)
  unsigned short* AO    = x_bf;                                // alias, see above

  cast_fused<<<dim3(1024, 5), 256, 0, stream>>>(x, Wq, Wk, Wv, Wo, x_bf, wqkv, wo_bf);

  gemm_bt<0><<<(MTOK/128) * (3*DIM/128), 256, 0, stream>>>(
      x_bf, wqkv, MTOK, 3*DIM, DIM, 3*DIM/128, Qb, Kb, Vt, nullptr);

  attn_fwd<<<dim3(SEQ/32, BATCH*NH), 64, 0, stream>>>(Qb, Kb, Vt, AO);

  gemm_bt<1><<<(MTOK/128) * (DIM/128), 256, 0, stream>>>(
      AO, wo_bf, MTOK, DIM, DIM, DIM/128, nullptr, nullptr, nullptr, out);
}